// Round 6
// baseline (141.049 us; speedup 1.0000x reference)
//
#include <hip/hip_runtime.h>

// LIF scan, B=65536 x L=400. Round 6: wave specialization with raw barriers.
// Lessons encoded:
//   r4: nontemporal stores = 2.4x write amplification -> plain stores (L2 merges;
//       harness fill kernel sustains 7.1 TB/s stores at 10% occupancy).
//   r4: __syncthreads drains vmcnt(0) every chunk -> kills compute wave's
//       prefetch and forces store-drain onto the critical path. Replace with
//       s_waitcnt lgkmcnt(0) (writer) + raw s_barrier: LDS ordering needs
//       lgkmcnt only; in-flight global loads/stores survive the barrier.
//   r5: two-kernel split serializes scan and store phases -> fuse, 2 waves/SIMD.
// Block = 128 threads = {wave0: scan 64 rows, wave1: expand+store}; grid 1024.
// Compute wave: double-buffered direct-to-reg loads (VGPR<=256 so both waves
// stay resident), pure-reg scan, bit-packed spikes (80b -> 3 u32) into
// double-buffered LDS. Store wave: unpack -> coalesced full-line f4 stores.
// div20 = Markstein 2-fma correctly-rounded v/20 (validated r3-r5: absmax 2.0
// vs threshold 7.2).

#define L_LEN 400
#define TC 80
#define NC 5
#define F4C 20
#define BIG 0x7fffffff

typedef float f4 __attribute__((ext_vector_type(4)));

__device__ __forceinline__ float div20(float v) {
    const float c = 0.05f;
    float q = v * c;
    float r = fmaf(-20.0f, q, v);
    return fmaf(r, c, q);
}

__device__ __forceinline__ void load_chunk(const float* __restrict__ I, int row,
                                           int c, f4* regs) {
#pragma unroll
    for (int k = 0; k < F4C; ++k)
        regs[k] = *reinterpret_cast<const f4*>(
            I + (size_t)row * L_LEN + c * TC + k * 4);
}

struct ScanState {
    float v;
    int num;
    int cnt;
    int first;
};

__device__ __forceinline__ void scan_chunk(const f4* in, int cbase,
                                           ScanState& st, unsigned* bw) {
    unsigned b0 = 0, b1 = 0, b2 = 0;
    int numL = 0;
#pragma unroll
    for (int k = 0; k < F4C; ++k) {
#pragma unroll
        for (int m = 0; m < 4; ++m) {
            const int tl = k * 4 + m;
            float x = in[k][m];
            // reference association: v = v + ((-v/20) + x)
            float d  = x - div20(st.v);
            float vn = st.v + d;
            bool fire = vn >= 1.0f;
            numL = fire ? numL + tl : numL;
            if (tl < 32)      b0 |= fire ? (1u << tl) : 0u;
            else if (tl < 64) b1 |= fire ? (1u << (tl - 32)) : 0u;
            else              b2 |= fire ? (1u << (tl - 64)) : 0u;
            st.v = fire ? 0.0f : vn;
        }
    }
    int cntC = __builtin_popcount(b0) + __builtin_popcount(b1) +
               __builtin_popcount(b2);
    int fl = b0 ? __builtin_ctz(b0)
           : (b1 ? 32 + __builtin_ctz(b1)
           : (b2 ? 64 + __builtin_ctz(b2) : -1));
    st.num += numL + cbase * cntC;
    st.cnt += cntC;
    st.first = min(st.first, fl >= 0 ? cbase + fl : BIG);
    bw[0] = b0; bw[1] = b1; bw[2] = b2;
}

__global__ __launch_bounds__(128, 2) void lif_kernel(const float* __restrict__ I,
                                                     float* __restrict__ spikes,
                                                     float* __restrict__ hard_lat,
                                                     float* __restrict__ soft_lat) {
    __shared__ unsigned bits[2][64][3];
    const int lane = threadIdx.x & 63;
    const int wid  = threadIdx.x >> 6;    // wave-uniform: 0=scan, 1=store
    const int R0 = blockIdx.x * 64;
    const int row = R0 + lane;

    f4 A[F4C], Bb[F4C];
    ScanState st;
    st.v = 0.0f; st.num = 0; st.cnt = 0; st.first = BIG;

    if (wid == 0) {
        load_chunk(I, row, 0, A);
        load_chunk(I, row, 1, Bb);
    }

    for (int c = 0; c < NC; ++c) {
        if (wid == 0) {
            unsigned bw[3];
            if ((c & 1) == 0) {
                scan_chunk(A, c * TC, st, bw);
                if (c + 2 < NC) load_chunk(I, row, c + 2, A);
            } else {
                scan_chunk(Bb, c * TC, st, bw);
                if (c + 2 < NC) load_chunk(I, row, c + 2, Bb);
            }
            bits[c & 1][lane][0] = bw[0];
            bits[c & 1][lane][1] = bw[1];
            bits[c & 1][lane][2] = bw[2];
            // make ds_writes visible to wave1 WITHOUT draining vmcnt (keeps
            // prefetch loads in flight across the barrier)
            asm volatile("s_waitcnt lgkmcnt(0)" ::: "memory");
        }
        asm volatile("s_barrier" ::: "memory");
        if (wid == 1) {
#pragma unroll
            for (int i = 0; i < F4C; ++i) {
                int flat = i * 64 + lane;       // 0..1279
                int rl = flat / F4C;
                int k  = flat % F4C;
                unsigned w = bits[c & 1][rl][k >> 3];
                int sh = (4 * k) & 31;
                f4 s;
                s.x = (float)((w >> (sh + 0)) & 1u);
                s.y = (float)((w >> (sh + 1)) & 1u);
                s.z = (float)((w >> (sh + 2)) & 1u);
                s.w = (float)((w >> (sh + 3)) & 1u);
                *reinterpret_cast<f4*>(
                    spikes + (size_t)(R0 + rl) * L_LEN + c * TC + k * 4) = s;
            }
        }
    }

    if (wid == 0) {
        hard_lat[row] = (float)(st.first == BIG ? 0 : st.first);
        soft_lat[row] = (float)st.num / ((float)st.cnt + 1e-6f);
    }
}

extern "C" void kernel_launch(void* const* d_in, const int* in_sizes, int n_in,
                              void* d_out, int out_size, void* d_ws, size_t ws_size,
                              hipStream_t stream) {
    const float* I = (const float*)d_in[0];
    int B = in_sizes[0] / L_LEN;  // 65536

    float* spk = (float*)d_out;
    float* hard = spk + (size_t)B * L_LEN;
    float* soft = hard + B;

    dim3 block(128);
    dim3 grid(B / 64);
    hipLaunchKernelGGL(lif_kernel, grid, block, 0, stream, I, spk, hard, soft);
}

// Round 7
// 140.284 us; speedup vs baseline: 1.0055x; 1.0055x over previous
//
#include <hip/hip_runtime.h>

// LIF scan, B=65536 x L=400. Round 7: wave specialization + per-chunk store drain.
// Mystery from r4/r6: dedicated store wave -> WRITE 251MB (2.4x) + FETCH +94MB,
// with OR without nontemporal stores. Common variable: store wave never waits
// on vmcnt, so ~100 store instructions pile up in flight. In every clean run
// (r2/r3/r5, WRITE=106MB) program order forced a vmcnt drain of prior stores
// each chunk (in-order vmcnt: scan's load-wait drains older stores too).
// Hypothesis: extreme outstanding-store depth defeats L2 line merging ->
// partial-line retirement -> RFO fetch + double writeback.
// Single change vs r6: wave1 executes s_waitcnt vmcnt(0) after each chunk's
// 20 stores (<=1 chunk outstanding; drain hides under wave0's ~2400cy scan).
// Everything else identical: block=128 {wave0 scan, wave1 store}, raw s_barrier
// + lgkmcnt-only on wave0 side (keeps wave0's prefetch loads in flight),
// bit-packed spikes through double-buffered LDS, plain full-line f4 stores.
// div20 = Markstein 2-fma correctly-rounded v/20 (validated r3-r6).

#define L_LEN 400
#define TC 80
#define NC 5
#define F4C 20
#define BIG 0x7fffffff

typedef float f4 __attribute__((ext_vector_type(4)));

__device__ __forceinline__ float div20(float v) {
    const float c = 0.05f;
    float q = v * c;
    float r = fmaf(-20.0f, q, v);
    return fmaf(r, c, q);
}

__device__ __forceinline__ void load_chunk(const float* __restrict__ I, int row,
                                           int c, f4* regs) {
#pragma unroll
    for (int k = 0; k < F4C; ++k)
        regs[k] = *reinterpret_cast<const f4*>(
            I + (size_t)row * L_LEN + c * TC + k * 4);
}

struct ScanState {
    float v;
    int num;
    int cnt;
    int first;
};

__device__ __forceinline__ void scan_chunk(const f4* in, int cbase,
                                           ScanState& st, unsigned* bw) {
    unsigned b0 = 0, b1 = 0, b2 = 0;
    int numL = 0;
#pragma unroll
    for (int k = 0; k < F4C; ++k) {
#pragma unroll
        for (int m = 0; m < 4; ++m) {
            const int tl = k * 4 + m;
            float x = in[k][m];
            // reference association: v = v + ((-v/20) + x)
            float d  = x - div20(st.v);
            float vn = st.v + d;
            bool fire = vn >= 1.0f;
            numL = fire ? numL + tl : numL;
            if (tl < 32)      b0 |= fire ? (1u << tl) : 0u;
            else if (tl < 64) b1 |= fire ? (1u << (tl - 32)) : 0u;
            else              b2 |= fire ? (1u << (tl - 64)) : 0u;
            st.v = fire ? 0.0f : vn;
        }
    }
    int cntC = __builtin_popcount(b0) + __builtin_popcount(b1) +
               __builtin_popcount(b2);
    int fl = b0 ? __builtin_ctz(b0)
           : (b1 ? 32 + __builtin_ctz(b1)
           : (b2 ? 64 + __builtin_ctz(b2) : -1));
    st.num += numL + cbase * cntC;
    st.cnt += cntC;
    st.first = min(st.first, fl >= 0 ? cbase + fl : BIG);
    bw[0] = b0; bw[1] = b1; bw[2] = b2;
}

__global__ __launch_bounds__(128, 2) void lif_kernel(const float* __restrict__ I,
                                                     float* __restrict__ spikes,
                                                     float* __restrict__ hard_lat,
                                                     float* __restrict__ soft_lat) {
    __shared__ unsigned bits[2][64][3];
    const int lane = threadIdx.x & 63;
    const int wid  = threadIdx.x >> 6;    // wave-uniform: 0=scan, 1=store
    const int R0 = blockIdx.x * 64;
    const int row = R0 + lane;

    f4 A[F4C], Bb[F4C];
    ScanState st;
    st.v = 0.0f; st.num = 0; st.cnt = 0; st.first = BIG;

    if (wid == 0) {
        load_chunk(I, row, 0, A);
        load_chunk(I, row, 1, Bb);
    }

    for (int c = 0; c < NC; ++c) {
        if (wid == 0) {
            unsigned bw[3];
            if ((c & 1) == 0) {
                scan_chunk(A, c * TC, st, bw);
                if (c + 2 < NC) load_chunk(I, row, c + 2, A);
            } else {
                scan_chunk(Bb, c * TC, st, bw);
                if (c + 2 < NC) load_chunk(I, row, c + 2, Bb);
            }
            bits[c & 1][lane][0] = bw[0];
            bits[c & 1][lane][1] = bw[1];
            bits[c & 1][lane][2] = bw[2];
            // make ds_writes visible WITHOUT draining vmcnt (prefetch loads
            // stay in flight across the barrier)
            asm volatile("s_waitcnt lgkmcnt(0)" ::: "memory");
        }
        asm volatile("s_barrier" ::: "memory");
        if (wid == 1) {
#pragma unroll
            for (int i = 0; i < F4C; ++i) {
                int flat = i * 64 + lane;       // 0..1279
                int rl = flat / F4C;
                int k  = flat % F4C;
                unsigned w = bits[c & 1][rl][k >> 3];
                int sh = (4 * k) & 31;
                f4 s;
                s.x = (float)((w >> (sh + 0)) & 1u);
                s.y = (float)((w >> (sh + 1)) & 1u);
                s.z = (float)((w >> (sh + 2)) & 1u);
                s.w = (float)((w >> (sh + 3)) & 1u);
                *reinterpret_cast<f4*>(
                    spikes + (size_t)(R0 + rl) * L_LEN + c * TC + k * 4) = s;
            }
            // THE one change vs r6: drain this chunk's stores before looping.
            // Keeps outstanding-store depth <= 1 chunk (r3's cadence); the
            // wait hides under wave0's next-chunk scan.
            asm volatile("s_waitcnt vmcnt(0)" ::: "memory");
        }
    }

    if (wid == 0) {
        hard_lat[row] = (float)(st.first == BIG ? 0 : st.first);
        soft_lat[row] = (float)st.num / ((float)st.cnt + 1e-6f);
    }
}

extern "C" void kernel_launch(void* const* d_in, const int* in_sizes, int n_in,
                              void* d_out, int out_size, void* d_ws, size_t ws_size,
                              hipStream_t stream) {
    const float* I = (const float*)d_in[0];
    int B = in_sizes[0] / L_LEN;  // 65536

    float* spk = (float*)d_out;
    float* hard = spk + (size_t)B * L_LEN;
    float* soft = hard + B;

    dim3 block(128);
    dim3 grid(B / 64);
    hipLaunchKernelGGL(lif_kernel, grid, block, 0, stream, I, spk, hard, soft);
}

// Round 8
// 41.332 us; speedup vs baseline: 3.4125x; 3.3940x over previous
//
#include <hip/hip_runtime.h>

// LIF scan, B=65536 x L=400. Round 8: fully-coalesced loads via swizzled LDS.
// Evidence ledger:
//   r3 (fused 1-wave, reg loads): 42.2us, FETCH 58MB, WRITE 106MB  <- base
//   r4/r6/r7: dedicated store wave => WRITE 251MB + FETCH 152MB regardless of
//       nt/drain -> store-wave structure abandoned for good.
//   r5: kernel split serializes -> 48us.
// Remaining dirty pattern in r3: per-lane row loads scatter each load instr
// across 64 cache lines (16B/line used, 4x L2 request rate). This round:
//   - coop coalesced global->reg (1KB contiguous per instr; (r,k) walker with
//     incremental addresses, same mapping as the proven store loop)
//   - reg->LDS at pitch 96 floats with slot swizzle (k ^ (r&7)): scan-side
//     ds_read_b128 is exactly 8 words/bank = conflict-free minimum
//   - single LDS input buffer (25KB total -> 4 blocks/CU) + register prefetch
//     of next chunk under the scan; single wave -> no barriers, in-order DS.
//   - scan, bit-pack, bits->LDS, coalesced full-line stores: unchanged (r3).
// div20 = Markstein 2-fma correctly-rounded v/20 (absmax 2.0 == IEEE-div runs).

#define L_LEN 400
#define TC 80
#define NC 5
#define F4C 20
#define PITCHF 96            // LDS row pitch in floats (24 f4 slots)
#define BIG 0x7fffffff

typedef float f4 __attribute__((ext_vector_type(4)));

__device__ __forceinline__ float div20(float v) {
    const float c = 0.05f;
    float q = v * c;
    float r = fmaf(-20.0f, q, v);
    return fmaf(r, c, q);
}

__global__ __launch_bounds__(64, 1) void lif_kernel(const float* __restrict__ I,
                                                    float* __restrict__ spikes,
                                                    float* __restrict__ hard_lat,
                                                    float* __restrict__ soft_lat) {
    __shared__ float lds_in[64 * PITCHF];   // 24576 B
    __shared__ unsigned bitsb[64 * 3];      // 768 B
    const int j = threadIdx.x;
    const int R0 = blockIdx.x * 64;
    const char* Ib = (const char*)I + (size_t)R0 * 1600;
    char* Sb = (char*)spikes + (size_t)R0 * 1600;

    // coalesced walker start: flat = j -> (r0, k0)
    const int r0 = j / 20;
    const int k0 = j - r0 * 20;

    f4 regs[F4C];

    // coalesced global->reg: instr i covers flats [i*64, i*64+64) = 1KB contig
    auto load_coal = [&](int c, f4* rg) {
        int r = r0, k = k0;
        int off = r * 1600 + k * 16 + c * 320;
#pragma unroll
        for (int i = 0; i < F4C; ++i) {
            rg[i] = *reinterpret_cast<const f4*>(Ib + off);
            int kn = k + 4; bool cr = kn >= 20;
            k = cr ? kn - 20 : kn;
            r += cr ? 4 : 3;
            off += cr ? 6144 : 4864;
        }
    };

    // reg->LDS, swizzled slot (k ^ (r&7)) at pitch 96 floats
    auto write_lds = [&](const f4* rg) {
        int r = r0, k = k0;
#pragma unroll
        for (int i = 0; i < F4C; ++i) {
            *reinterpret_cast<f4*>(&lds_in[r * PITCHF + ((k ^ (r & 7)) << 2)]) = rg[i];
            int kn = k + 4; bool cr = kn >= 20;
            k = cr ? kn - 20 : kn;
            r += cr ? 4 : 3;
        }
    };

    load_coal(0, regs);
    write_lds(regs);

    float v = 0.0f;
    int num = 0, cnt = 0, first = BIG;
    float* myrow = &lds_in[j * PITCHF];
    const int jx = j & 7;

    for (int c = 0; c < NC; ++c) {
        if (c + 1 < NC) load_coal(c + 1, regs);   // prefetch under the scan

        // ---- scan chunk c from LDS (conflict-free swizzled b128 reads) ----
        unsigned b0 = 0, b1 = 0, b2 = 0;
        int numL = 0;
#pragma unroll
        for (int k = 0; k < F4C; ++k) {
            f4 x4 = *reinterpret_cast<const f4*>(&myrow[((k ^ jx) << 2)]);
#pragma unroll
            for (int m = 0; m < 4; ++m) {
                const int tl = k * 4 + m;
                float x = x4[m];
                // reference association: v = v + ((-v/20) + x)
                float d  = x - div20(v);
                float vn = v + d;
                bool fire = vn >= 1.0f;
                numL = fire ? numL + tl : numL;
                if (tl < 32)      b0 |= fire ? (1u << tl) : 0u;
                else if (tl < 64) b1 |= fire ? (1u << (tl - 32)) : 0u;
                else              b2 |= fire ? (1u << (tl - 64)) : 0u;
                v = fire ? 0.0f : vn;
            }
        }
        int cntC = __builtin_popcount(b0) + __builtin_popcount(b1) +
                   __builtin_popcount(b2);
        int fl = b0 ? __builtin_ctz(b0)
               : (b1 ? 32 + __builtin_ctz(b1)
               : (b2 ? 64 + __builtin_ctz(b2) : -1));
        int cbase = c * TC;
        num += numL + cbase * cntC;
        cnt += cntC;
        first = min(first, fl >= 0 ? cbase + fl : BIG);

        // ---- bits -> LDS, expand, coalesced full-line stores ----
        bitsb[j * 3 + 0] = b0;
        bitsb[j * 3 + 1] = b1;
        bitsb[j * 3 + 2] = b2;
        // single wave: DS ops in-order, no barrier needed
        {
            int r = r0, k = k0;
            int off = r * 1600 + k * 16 + c * 320;
#pragma unroll
            for (int i = 0; i < F4C; ++i) {
                unsigned w = bitsb[r * 3 + (k >> 3)];
                int sh = (k & 7) * 4;
                f4 s;
                s.x = (float)((w >> (sh + 0)) & 1u);
                s.y = (float)((w >> (sh + 1)) & 1u);
                s.z = (float)((w >> (sh + 2)) & 1u);
                s.w = (float)((w >> (sh + 3)) & 1u);
                *reinterpret_cast<f4*>(Sb + off) = s;
                int kn = k + 4; bool cr = kn >= 20;
                k = cr ? kn - 20 : kn;
                r += cr ? 4 : 3;
                off += cr ? 6144 : 4864;
            }
        }

        if (c + 1 < NC) write_lds(regs);   // after scan's ds_reads (in-order)
    }

    const int row = R0 + j;
    hard_lat[row] = (float)(first == BIG ? 0 : first);
    soft_lat[row] = (float)num / ((float)cnt + 1e-6f);
}

extern "C" void kernel_launch(void* const* d_in, const int* in_sizes, int n_in,
                              void* d_out, int out_size, void* d_ws, size_t ws_size,
                              hipStream_t stream) {
    const float* I = (const float*)d_in[0];
    int B = in_sizes[0] / L_LEN;  // 65536

    float* spk = (float*)d_out;
    float* hard = spk + (size_t)B * L_LEN;
    float* soft = hard + B;

    dim3 block(64);
    dim3 grid(B / 64);
    hipLaunchKernelGGL(lif_kernel, grid, block, 0, stream, I, spk, hard, soft);
}

// Round 9
// 41.310 us; speedup vs baseline: 3.4144x; 1.0006x over previous
//
#include <hip/hip_runtime.h>

// LIF scan, B=65536 x L=400. Round 9: ROLLED chunk loop (I-cache hypothesis).
// Evidence ledger:
//   r3 fused 1-wave reg-loads: 42.2us | r8 + coalesced LDS loads: 41.3us
//   -> two different memory structures, identical time => common fixed cost.
//   Stall audit: VALU-active 24%, HBM 63% of achievable; fill kernel does
//   7 TB/s stores at 10% occupancy => occupancy isn't the BW cap.
//   Hypothesis: fully-unrolled NC=5 x 80-step bodies = ~60KB straight-line
//   code > 32KB I-cache => every wave streams its text from L2 once, fetch
//   stalls dominate a 1-wave/SIMD kernel. Fix: #pragma unroll 1 on the c-loop
//   (code ~13KB, fits icache; iterations 2..5 run warm).
// Single variable vs r8; all memory paths identical.
// div20 = Markstein 2-fma correctly-rounded v/20 (validated r3-r8).

#define L_LEN 400
#define TC 80
#define NC 5
#define F4C 20
#define PITCHF 96
#define BIG 0x7fffffff

typedef float f4 __attribute__((ext_vector_type(4)));

__device__ __forceinline__ float div20(float v) {
    const float c = 0.05f;
    float q = v * c;
    float r = fmaf(-20.0f, q, v);
    return fmaf(r, c, q);
}

__global__ __launch_bounds__(64, 1) void lif_kernel(const float* __restrict__ I,
                                                    float* __restrict__ spikes,
                                                    float* __restrict__ hard_lat,
                                                    float* __restrict__ soft_lat) {
    __shared__ float lds_in[64 * PITCHF];   // 24576 B
    __shared__ unsigned bitsb[64 * 3];      // 768 B
    const int j = threadIdx.x;
    const int R0 = blockIdx.x * 64;
    const char* Ib = (const char*)I + (size_t)R0 * 1600;
    char* Sb = (char*)spikes + (size_t)R0 * 1600;

    const int r0 = j / 20;
    const int k0 = j - r0 * 20;

    f4 regs[F4C];

    auto load_coal = [&](int c, f4* rg) {
        int r = r0, k = k0;
        int off = r * 1600 + k * 16 + c * 320;
#pragma unroll
        for (int i = 0; i < F4C; ++i) {
            rg[i] = *reinterpret_cast<const f4*>(Ib + off);
            int kn = k + 4; bool cr = kn >= 20;
            k = cr ? kn - 20 : kn;
            r += cr ? 4 : 3;
            off += cr ? 6144 : 4864;
        }
    };

    auto write_lds = [&](const f4* rg) {
        int r = r0, k = k0;
#pragma unroll
        for (int i = 0; i < F4C; ++i) {
            *reinterpret_cast<f4*>(&lds_in[r * PITCHF + ((k ^ (r & 7)) << 2)]) = rg[i];
            int kn = k + 4; bool cr = kn >= 20;
            k = cr ? kn - 20 : kn;
            r += cr ? 4 : 3;
        }
    };

    load_coal(0, regs);
    write_lds(regs);

    float v = 0.0f;
    int num = 0, cnt = 0, first = BIG;
    float* myrow = &lds_in[j * PITCHF];
    const int jx = j & 7;

#pragma unroll 1   // THE change vs r8: keep the chunk loop rolled (icache)
    for (int c = 0; c < NC; ++c) {
        if (c + 1 < NC) load_coal(c + 1, regs);

        // ---- scan chunk c from LDS (conflict-free swizzled b128 reads) ----
        unsigned b0 = 0, b1 = 0, b2 = 0;
        int numL = 0;
#pragma unroll
        for (int k = 0; k < F4C; ++k) {
            f4 x4 = *reinterpret_cast<const f4*>(&myrow[((k ^ jx) << 2)]);
#pragma unroll
            for (int m = 0; m < 4; ++m) {
                const int tl = k * 4 + m;
                float x = x4[m];
                // reference association: v = v + ((-v/20) + x)
                float d  = x - div20(v);
                float vn = v + d;
                bool fire = vn >= 1.0f;
                numL = fire ? numL + tl : numL;
                if (tl < 32)      b0 |= fire ? (1u << tl) : 0u;
                else if (tl < 64) b1 |= fire ? (1u << (tl - 32)) : 0u;
                else              b2 |= fire ? (1u << (tl - 64)) : 0u;
                v = fire ? 0.0f : vn;
            }
        }
        int cntC = __builtin_popcount(b0) + __builtin_popcount(b1) +
                   __builtin_popcount(b2);
        int fl = b0 ? __builtin_ctz(b0)
               : (b1 ? 32 + __builtin_ctz(b1)
               : (b2 ? 64 + __builtin_ctz(b2) : -1));
        int cbase = c * TC;
        num += numL + cbase * cntC;
        cnt += cntC;
        first = min(first, fl >= 0 ? cbase + fl : BIG);

        // ---- bits -> LDS, expand, coalesced full-line stores ----
        bitsb[j * 3 + 0] = b0;
        bitsb[j * 3 + 1] = b1;
        bitsb[j * 3 + 2] = b2;
        {
            int r = r0, k = k0;
            int off = r * 1600 + k * 16 + c * 320;
#pragma unroll
            for (int i = 0; i < F4C; ++i) {
                unsigned w = bitsb[r * 3 + (k >> 3)];
                int sh = (k & 7) * 4;
                f4 s;
                s.x = (float)((w >> (sh + 0)) & 1u);
                s.y = (float)((w >> (sh + 1)) & 1u);
                s.z = (float)((w >> (sh + 2)) & 1u);
                s.w = (float)((w >> (sh + 3)) & 1u);
                *reinterpret_cast<f4*>(Sb + off) = s;
                int kn = k + 4; bool cr = kn >= 20;
                k = cr ? kn - 20 : kn;
                r += cr ? 4 : 3;
                off += cr ? 6144 : 4864;
            }
        }

        if (c + 1 < NC) write_lds(regs);
    }

    const int row = R0 + j;
    hard_lat[row] = (float)(first == BIG ? 0 : first);
    soft_lat[row] = (float)num / ((float)cnt + 1e-6f);
}

extern "C" void kernel_launch(void* const* d_in, const int* in_sizes, int n_in,
                              void* d_out, int out_size, void* d_ws, size_t ws_size,
                              hipStream_t stream) {
    const float* I = (const float*)d_in[0];
    int B = in_sizes[0] / L_LEN;  // 65536

    float* spk = (float*)d_out;
    float* hard = spk + (size_t)B * L_LEN;
    float* soft = hard + B;

    dim3 block(64);
    dim3 grid(B / 64);
    hipLaunchKernelGGL(lif_kernel, grid, block, 0, stream, I, spk, hard, soft);
}

// Round 10
// 38.837 us; speedup vs baseline: 3.6318x; 1.0637x over previous
//
#include <hip/hip_runtime.h>

// LIF scan, B=65536 x L=400. Round 10: nt stores on the PROVEN single-wave
// structure (single-variable test).
// Evidence ledger:
//   r3/r8/r9 fused 1-wave: 41.3-42.2us, FETCH 59MB, WRITE 105MB (clean)
//   r4(nt+store-wave) and r6(plain+store-wave) BOTH wrote 251MB -> the
//     store-wave structure was the poison; nt was never isolated.
//   r9: rolled loop identical -> icache exonerated.
//   Accounting: 210MB/call; warm HBM=164MB (output write-allocs evict ~56% of
//     the input from the 256MB L3 every replay). If spike stores stream PAST
//     L3, input stays L3-resident -> HBM ~ writes only -> floor ~17-20us.
// Single change vs r9: __builtin_nontemporal_store on the 20 full-line spike
// stores (each instr covers 4 complete 64B lines -> no partial-line risk).
// Prediction: WRITE ~105MB, FETCH -> <25MB, dur 30-35us. If WRITE >= 150MB:
// nt is intrinsically pathological -> revert, try burst smoothing.
// div20 = Markstein 2-fma correctly-rounded v/20 (validated r3-r9).

#define L_LEN 400
#define TC 80
#define NC 5
#define F4C 20
#define PITCHF 96
#define BIG 0x7fffffff

typedef float f4 __attribute__((ext_vector_type(4)));

__device__ __forceinline__ float div20(float v) {
    const float c = 0.05f;
    float q = v * c;
    float r = fmaf(-20.0f, q, v);
    return fmaf(r, c, q);
}

__global__ __launch_bounds__(64, 1) void lif_kernel(const float* __restrict__ I,
                                                    float* __restrict__ spikes,
                                                    float* __restrict__ hard_lat,
                                                    float* __restrict__ soft_lat) {
    __shared__ float lds_in[64 * PITCHF];   // 24576 B
    __shared__ unsigned bitsb[64 * 3];      // 768 B
    const int j = threadIdx.x;
    const int R0 = blockIdx.x * 64;
    const char* Ib = (const char*)I + (size_t)R0 * 1600;
    char* Sb = (char*)spikes + (size_t)R0 * 1600;

    const int r0 = j / 20;
    const int k0 = j - r0 * 20;

    f4 regs[F4C];

    auto load_coal = [&](int c, f4* rg) {
        int r = r0, k = k0;
        int off = r * 1600 + k * 16 + c * 320;
#pragma unroll
        for (int i = 0; i < F4C; ++i) {
            rg[i] = *reinterpret_cast<const f4*>(Ib + off);
            int kn = k + 4; bool cr = kn >= 20;
            k = cr ? kn - 20 : kn;
            r += cr ? 4 : 3;
            off += cr ? 6144 : 4864;
        }
    };

    auto write_lds = [&](const f4* rg) {
        int r = r0, k = k0;
#pragma unroll
        for (int i = 0; i < F4C; ++i) {
            *reinterpret_cast<f4*>(&lds_in[r * PITCHF + ((k ^ (r & 7)) << 2)]) = rg[i];
            int kn = k + 4; bool cr = kn >= 20;
            k = cr ? kn - 20 : kn;
            r += cr ? 4 : 3;
        }
    };

    load_coal(0, regs);
    write_lds(regs);

    float v = 0.0f;
    int num = 0, cnt = 0, first = BIG;
    float* myrow = &lds_in[j * PITCHF];
    const int jx = j & 7;

#pragma unroll 1
    for (int c = 0; c < NC; ++c) {
        if (c + 1 < NC) load_coal(c + 1, regs);

        // ---- scan chunk c from LDS (conflict-free swizzled b128 reads) ----
        unsigned b0 = 0, b1 = 0, b2 = 0;
        int numL = 0;
#pragma unroll
        for (int k = 0; k < F4C; ++k) {
            f4 x4 = *reinterpret_cast<const f4*>(&myrow[((k ^ jx) << 2)]);
#pragma unroll
            for (int m = 0; m < 4; ++m) {
                const int tl = k * 4 + m;
                float x = x4[m];
                // reference association: v = v + ((-v/20) + x)
                float d  = x - div20(v);
                float vn = v + d;
                bool fire = vn >= 1.0f;
                numL = fire ? numL + tl : numL;
                if (tl < 32)      b0 |= fire ? (1u << tl) : 0u;
                else if (tl < 64) b1 |= fire ? (1u << (tl - 32)) : 0u;
                else              b2 |= fire ? (1u << (tl - 64)) : 0u;
                v = fire ? 0.0f : vn;
            }
        }
        int cntC = __builtin_popcount(b0) + __builtin_popcount(b1) +
                   __builtin_popcount(b2);
        int fl = b0 ? __builtin_ctz(b0)
               : (b1 ? 32 + __builtin_ctz(b1)
               : (b2 ? 64 + __builtin_ctz(b2) : -1));
        int cbase = c * TC;
        num += numL + cbase * cntC;
        cnt += cntC;
        first = min(first, fl >= 0 ? cbase + fl : BIG);

        // ---- bits -> LDS, expand, coalesced full-line NT stores ----
        bitsb[j * 3 + 0] = b0;
        bitsb[j * 3 + 1] = b1;
        bitsb[j * 3 + 2] = b2;
        {
            int r = r0, k = k0;
            int off = r * 1600 + k * 16 + c * 320;
#pragma unroll
            for (int i = 0; i < F4C; ++i) {
                unsigned w = bitsb[r * 3 + (k >> 3)];
                int sh = (k & 7) * 4;
                f4 s;
                s.x = (float)((w >> (sh + 0)) & 1u);
                s.y = (float)((w >> (sh + 1)) & 1u);
                s.z = (float)((w >> (sh + 2)) & 1u);
                s.w = (float)((w >> (sh + 3)) & 1u);
                __builtin_nontemporal_store(s, reinterpret_cast<f4*>(Sb + off));
                int kn = k + 4; bool cr = kn >= 20;
                k = cr ? kn - 20 : kn;
                r += cr ? 4 : 3;
                off += cr ? 6144 : 4864;
            }
        }

        if (c + 1 < NC) write_lds(regs);
    }

    const int row = R0 + j;
    hard_lat[row] = (float)(first == BIG ? 0 : first);
    soft_lat[row] = (float)num / ((float)cnt + 1e-6f);
}

extern "C" void kernel_launch(void* const* d_in, const int* in_sizes, int n_in,
                              void* d_out, int out_size, void* d_ws, size_t ws_size,
                              hipStream_t stream) {
    const float* I = (const float*)d_in[0];
    int B = in_sizes[0] / L_LEN;  // 65536

    float* spk = (float*)d_out;
    float* hard = spk + (size_t)B * L_LEN;
    float* soft = hard + B;

    dim3 block(64);
    dim3 grid(B / 64);
    hipLaunchKernelGGL(lif_kernel, grid, block, 0, stream, I, spk, hard, soft);
}